// Round 1
// baseline (1123.312 us; speedup 1.0000x reference)
//
#include <hip/hip_runtime.h>
#include <hip/hip_bf16.h>
#include <math.h>

#define B_SZ 256
#define H_SZ 1024
#define L_SZ 10
#define V_SZ 50257

// ---------------------------------------------------------------------------
// Kernel 1: embedding gather + attention logits + softmax + context vector.
// One block per batch element. Writes cat = [embedded | attn_applied] (B,2H)
// and attn_weights (B,L).
// ---------------------------------------------------------------------------
__global__ __launch_bounds__(256) void attn_kernel(
    const int* __restrict__ tokens, const float* __restrict__ hidden,
    const float* __restrict__ enc, const float* __restrict__ emb,
    const float* __restrict__ attn_W, const float* __restrict__ attn_b,
    float* __restrict__ cat_out, float* __restrict__ attn_w_out)
{
    const int b = blockIdx.x;
    const int tid = threadIdx.x;
    const int tok = tokens[b];
    const float* erow = emb + (size_t)tok * H_SZ;
    const float* hrow = hidden + (size_t)b * H_SZ;

    __shared__ float red[L_SZ][256];
    __shared__ float wts[L_SZ];

    float acc[L_SZ];
#pragma unroll
    for (int l = 0; l < L_SZ; ++l) acc[l] = 0.f;

    for (int i = tid; i < H_SZ; i += 256) {
        float e = erow[i];
        float hv = hrow[i];
        cat_out[(size_t)b * 2 * H_SZ + i] = e;  // store embedded half
#pragma unroll
        for (int l = 0; l < L_SZ; ++l) {
            acc[l] += e * attn_W[l * 2 * H_SZ + i] + hv * attn_W[l * 2 * H_SZ + H_SZ + i];
        }
    }
#pragma unroll
    for (int l = 0; l < L_SZ; ++l) red[l][tid] = acc[l];
    __syncthreads();
    for (int s = 128; s > 0; s >>= 1) {
        if (tid < s) {
#pragma unroll
            for (int l = 0; l < L_SZ; ++l) red[l][tid] += red[l][tid + s];
        }
        __syncthreads();
    }
    if (tid == 0) {
        float m = -INFINITY;
        float lg[L_SZ];
#pragma unroll
        for (int l = 0; l < L_SZ; ++l) {
            lg[l] = red[l][0] + attn_b[l];
            m = fmaxf(m, lg[l]);
        }
        float s = 0.f;
#pragma unroll
        for (int l = 0; l < L_SZ; ++l) {
            float e = expf(lg[l] - m);
            wts[l] = e;
            s += e;
        }
        float inv = 1.f / s;
#pragma unroll
        for (int l = 0; l < L_SZ; ++l) {
            wts[l] *= inv;
            attn_w_out[(size_t)b * L_SZ + l] = wts[l];
        }
    }
    __syncthreads();

    for (int i = tid; i < H_SZ; i += 256) {
        float s = 0.f;
#pragma unroll
        for (int l = 0; l < L_SZ; ++l) s += wts[l] * enc[l * H_SZ + i];
        cat_out[(size_t)b * 2 * H_SZ + H_SZ + i] = s;  // attn_applied half
    }
}

// ---------------------------------------------------------------------------
// Generic tiled fp32 GEMM: C[M,N] = A[M,K] @ W[N,K]^T + bias, optional ReLU.
// BM=BN=64, BK=16, 256 threads, 4x4 micro-tile per thread.
// Requires: M % 64 == 0, K % 16 == 0. N guarded.
// ---------------------------------------------------------------------------
#define BM 64
#define BN 64
#define BK 16

__global__ __launch_bounds__(256) void gemm_bt(
    const float* __restrict__ A, const float* __restrict__ W,
    const float* __restrict__ bias, float* __restrict__ C,
    int M, int N, int K, int relu)
{
    __shared__ float As[BK][BM];
    __shared__ float Ws[BK][BN];

    const int tid = threadIdx.x;
    const int n0 = blockIdx.x * BN;
    const int m0 = blockIdx.y * BM;

    const int lr = tid >> 2;         // 0..63: row within tile
    const int lc = (tid & 3) * 4;    // 0,4,8,12: k-offset (float4)
    const int tx = tid & 15;         // 0..15
    const int ty = tid >> 4;         // 0..15

    float acc[4][4] = {};

    for (int k0 = 0; k0 < K; k0 += BK) {
        float4 av = *(const float4*)(A + (size_t)(m0 + lr) * K + k0 + lc);
        float4 wv;
        int wrow = n0 + lr;
        if (wrow < N) {
            wv = *(const float4*)(W + (size_t)wrow * K + k0 + lc);
        } else {
            wv = make_float4(0.f, 0.f, 0.f, 0.f);
        }
        __syncthreads();  // WAR guard vs previous iteration's compute
        As[lc + 0][lr] = av.x; As[lc + 1][lr] = av.y;
        As[lc + 2][lr] = av.z; As[lc + 3][lr] = av.w;
        Ws[lc + 0][lr] = wv.x; Ws[lc + 1][lr] = wv.y;
        Ws[lc + 2][lr] = wv.z; Ws[lc + 3][lr] = wv.w;
        __syncthreads();
#pragma unroll
        for (int kk = 0; kk < BK; ++kk) {
            float a[4], w[4];
#pragma unroll
            for (int i = 0; i < 4; ++i) a[i] = As[kk][ty * 4 + i];
#pragma unroll
            for (int j = 0; j < 4; ++j) w[j] = Ws[kk][tx * 4 + j];
#pragma unroll
            for (int i = 0; i < 4; ++i)
#pragma unroll
                for (int j = 0; j < 4; ++j) acc[i][j] += a[i] * w[j];
        }
    }

#pragma unroll
    for (int i = 0; i < 4; ++i) {
        int m = m0 + ty * 4 + i;
#pragma unroll
        for (int j = 0; j < 4; ++j) {
            int n = n0 + tx * 4 + j;
            if (n < N) {
                float v = acc[i][j] + (bias ? bias[n] : 0.f);
                if (relu) v = fmaxf(v, 0.f);
                C[(size_t)m * N + n] = v;
            }
        }
    }
}

// ---------------------------------------------------------------------------
// GRU pointwise combine: r,z,n gates -> h_new
// ---------------------------------------------------------------------------
__global__ __launch_bounds__(256) void gru_combine(
    const float* __restrict__ gi, const float* __restrict__ gh,
    const float* __restrict__ hidden, float* __restrict__ h_new)
{
    int idx = blockIdx.x * blockDim.x + threadIdx.x;
    if (idx >= B_SZ * H_SZ) return;
    int b = idx >> 10;          // / H_SZ
    int j = idx & (H_SZ - 1);   // % H_SZ
    const float* gib = gi + (size_t)b * 3 * H_SZ;
    const float* ghb = gh + (size_t)b * 3 * H_SZ;
    float i_r = gib[j], i_z = gib[H_SZ + j], i_n = gib[2 * H_SZ + j];
    float h_r = ghb[j], h_z = ghb[H_SZ + j], h_n = ghb[2 * H_SZ + j];
    float r = 1.f / (1.f + expf(-(i_r + h_r)));
    float z = 1.f / (1.f + expf(-(i_z + h_z)));
    float n = tanhf(i_n + r * h_n);
    float h = hidden[idx];
    h_new[idx] = (1.f - z) * n + z * h;
}

// ---------------------------------------------------------------------------
// In-place log-softmax over V per row. One block per row.
// ---------------------------------------------------------------------------
__global__ __launch_bounds__(256) void logsoftmax_kernel(float* __restrict__ out, int V)
{
    int b = blockIdx.x;
    float* row = out + (size_t)b * V;
    int tid = threadIdx.x;
    __shared__ float red[256];

    float m = -INFINITY;
    for (int v = tid; v < V; v += 256) m = fmaxf(m, row[v]);
    red[tid] = m;
    __syncthreads();
    for (int s = 128; s > 0; s >>= 1) {
        if (tid < s) red[tid] = fmaxf(red[tid], red[tid + s]);
        __syncthreads();
    }
    m = red[0];
    __syncthreads();

    float sum = 0.f;
    for (int v = tid; v < V; v += 256) sum += expf(row[v] - m);
    red[tid] = sum;
    __syncthreads();
    for (int s = 128; s > 0; s >>= 1) {
        if (tid < s) red[tid] += red[tid + s];
        __syncthreads();
    }
    float lse = m + logf(red[0]);

    for (int v = tid; v < V; v += 256) row[v] -= lse;
}

// ---------------------------------------------------------------------------
extern "C" void kernel_launch(void* const* d_in, const int* in_sizes, int n_in,
                              void* d_out, int out_size, void* d_ws, size_t ws_size,
                              hipStream_t stream)
{
    const int*   tokens = (const int*)d_in[0];
    const float* hidden = (const float*)d_in[1];
    const float* enc    = (const float*)d_in[2];
    const float* emb    = (const float*)d_in[3];
    const float* attn_W = (const float*)d_in[4];
    const float* attn_b = (const float*)d_in[5];
    const float* comb_W = (const float*)d_in[6];
    const float* comb_b = (const float*)d_in[7];
    const float* W_ih   = (const float*)d_in[8];
    const float* W_hh   = (const float*)d_in[9];
    const float* b_ih   = (const float*)d_in[10];
    const float* b_hh   = (const float*)d_in[11];
    const float* out_W  = (const float*)d_in[12];
    const float* out_b  = (const float*)d_in[13];

    float* out = (float*)d_out;
    float* logits     = out;                                   // [B,V]
    float* h_new      = out + (size_t)B_SZ * V_SZ;             // [B,H]
    float* attn_w_out = h_new + (size_t)B_SZ * H_SZ;           // [B,L]

    // Scratch lives in out-region-0: it is dead by the time the big GEMM
    // overwrites region 0 with logits. No dependence on ws_size.
    float* cat = logits;                 // [B, 2H]
    float* x   = cat + (size_t)B_SZ * 2 * H_SZ;   // [B, H]
    float* gi  = x   + (size_t)B_SZ * H_SZ;       // [B, 3H]
    float* gh  = gi  + (size_t)B_SZ * 3 * H_SZ;   // [B, 3H]

    // 1) embedding + attention
    attn_kernel<<<B_SZ, 256, 0, stream>>>(tokens, hidden, enc, emb, attn_W, attn_b,
                                          cat, attn_w_out);
    // 2) x = relu(cat @ comb_W.T + comb_b)     [256 x 1024, K=2048]
    gemm_bt<<<dim3(H_SZ / BN, B_SZ / BM), 256, 0, stream>>>(
        cat, comb_W, comb_b, x, B_SZ, H_SZ, 2 * H_SZ, 1);
    // 3a) gi = x @ W_ih.T + b_ih               [256 x 3072, K=1024]
    gemm_bt<<<dim3(3 * H_SZ / BN, B_SZ / BM), 256, 0, stream>>>(
        x, W_ih, b_ih, gi, B_SZ, 3 * H_SZ, H_SZ, 0);
    // 3b) gh = h @ W_hh.T + b_hh               [256 x 3072, K=1024]
    gemm_bt<<<dim3(3 * H_SZ / BN, B_SZ / BM), 256, 0, stream>>>(
        hidden, W_hh, b_hh, gh, B_SZ, 3 * H_SZ, H_SZ, 0);
    // 3c) GRU combine -> h_new (out region 1)
    gru_combine<<<(B_SZ * H_SZ + 255) / 256, 256, 0, stream>>>(gi, gh, hidden, h_new);
    // 4) logits = h_new @ out_W.T + out_b      [256 x 50257, K=1024]
    gemm_bt<<<dim3((V_SZ + BN - 1) / BN, B_SZ / BM), 256, 0, stream>>>(
        h_new, out_W, out_b, logits, B_SZ, V_SZ, H_SZ, 0);
    // 5) in-place log_softmax over V
    logsoftmax_kernel<<<B_SZ, 256, 0, stream>>>(logits, V_SZ);
}

// Round 2
// 708.656 us; speedup vs baseline: 1.5851x; 1.5851x over previous
//
#include <hip/hip_runtime.h>
#include <hip/hip_bf16.h>
#include <math.h>
#include <stdint.h>

#define B_SZ 256
#define H_SZ 1024
#define L_SZ 10
#define V_SZ 50257

typedef __attribute__((ext_vector_type(8))) short short8;
typedef __attribute__((ext_vector_type(4))) float floatx4;

// fp32 -> bf16 bits, round-to-nearest-even
__device__ __forceinline__ unsigned f2bf_bits(float f) {
    unsigned u = __float_as_uint(f);
    return (u + 0x7FFFu + ((u >> 16) & 1u)) >> 16;
}

__device__ __forceinline__ short8 cvt8(float4 a, float4 b) {
    short8 r;
    r[0] = (short)f2bf_bits(a.x); r[1] = (short)f2bf_bits(a.y);
    r[2] = (short)f2bf_bits(a.z); r[3] = (short)f2bf_bits(a.w);
    r[4] = (short)f2bf_bits(b.x); r[5] = (short)f2bf_bits(b.y);
    r[6] = (short)f2bf_bits(b.z); r[7] = (short)f2bf_bits(b.w);
    return r;
}

// ---------------------------------------------------------------------------
// MFMA GEMM: C[M,N] = A[M,K] @ W[N,K]^T + bias (optional relu).
// 256 threads = 4 waves. Block tile: (MSUB*64) x 64, k-chunk 32.
//  MSUB=4: one block covers all M=256 rows -> W fetched from HBM exactly once.
//  MSUB=1: block covers 64 rows (for small-N GEMMs, more blocks).
// W is staged fp32->bf16 through LDS (stride 40 bf16 -> only 2-way bank
// aliasing, free). Next k-chunk's W is prefetched into registers during
// compute. A fragments are loaded straight from global (A is <=2 MB, L2-hot)
// and converted in-register.
// Fragment layouts (verified, learn_hip m89/m91):
//   A/B operand: elem [row = lane&15][k = (lane>>4)*8 + j]
//   C/D:         row = (lane>>4)*4 + reg, col = lane&15
// ---------------------------------------------------------------------------
#define WSTRIDE 40

template<int MSUB, int RELU>
__global__ __launch_bounds__(256) void gemm_mfma(
    const float* __restrict__ A, const float* __restrict__ W,
    const float* __restrict__ bias, float* __restrict__ C,
    int N, int K)
{
    __shared__ __align__(16) short lwb[64 * WSTRIDE];

    const int tid  = threadIdx.x;
    const int wave = tid >> 6;
    const int lane = tid & 63;
    const int quad = lane >> 4;
    const int l16  = lane & 15;

    const int n0 = blockIdx.x * 64;
    const int m_base = blockIdx.y * (MSUB * 64) + wave * (MSUB * 16);

    // W staging: thread t loads row (t>>2), 8 floats at col (t&3)*8
    const int wr = tid >> 2;
    const int wc = (tid & 3) * 8;
    const bool wvalid = (n0 + wr) < N;
    const float* wp = W + (size_t)(n0 + wr) * K + wc;

    float4 w0 = make_float4(0.f, 0.f, 0.f, 0.f), w1 = w0;
    if (wvalid) { w0 = *(const float4*)wp; w1 = *(const float4*)(wp + 4); }

    const float* arow[MSUB];
#pragma unroll
    for (int ms = 0; ms < MSUB; ++ms)
        arow[ms] = A + (size_t)(m_base + ms * 16 + l16) * K + quad * 8;

    floatx4 zero = {0.f, 0.f, 0.f, 0.f};
    floatx4 acc[MSUB][4];
#pragma unroll
    for (int ms = 0; ms < MSUB; ++ms)
#pragma unroll
        for (int ns = 0; ns < 4; ++ns) acc[ms][ns] = zero;

    for (int k0 = 0; k0 < K; k0 += 32) {
        __syncthreads();   // WAR: previous chunk's ds_reads done
        *(short8*)&lwb[wr * WSTRIDE + wc] = cvt8(w0, w1);
        __syncthreads();
        // prefetch next chunk's W while computing this one
        if (k0 + 32 < K && wvalid) {
            w0 = *(const float4*)(wp + k0 + 32);
            w1 = *(const float4*)(wp + k0 + 36);
        }
        short8 bfrag[4];
#pragma unroll
        for (int ns = 0; ns < 4; ++ns)
            bfrag[ns] = *(const short8*)&lwb[(ns * 16 + l16) * WSTRIDE + quad * 8];
#pragma unroll
        for (int ms = 0; ms < MSUB; ++ms) {
            float4 a0 = *(const float4*)(arow[ms] + k0);
            float4 a1 = *(const float4*)(arow[ms] + k0 + 4);
            short8 afrag = cvt8(a0, a1);
#pragma unroll
            for (int ns = 0; ns < 4; ++ns)
                acc[ms][ns] = __builtin_amdgcn_mfma_f32_16x16x32_bf16(
                    afrag, bfrag[ns], acc[ms][ns], 0, 0, 0);
        }
    }

    float bia[4];
#pragma unroll
    for (int ns = 0; ns < 4; ++ns) {
        int n = n0 + ns * 16 + l16;
        bia[ns] = (n < N) ? bias[n] : 0.f;
    }
#pragma unroll
    for (int ms = 0; ms < MSUB; ++ms) {
        int mb = m_base + ms * 16 + quad * 4;
#pragma unroll
        for (int ns = 0; ns < 4; ++ns) {
            int n = n0 + ns * 16 + l16;
            if (n < N) {
#pragma unroll
                for (int i = 0; i < 4; ++i) {
                    float v = acc[ms][ns][i] + bia[ns];
                    if (RELU) v = fmaxf(v, 0.f);
                    C[(size_t)(mb + i) * N + n] = v;
                }
            }
        }
    }
}

// ---------------------------------------------------------------------------
// Kernel 1: embedding gather + attention logits + softmax + context vector.
// ---------------------------------------------------------------------------
__global__ __launch_bounds__(256) void attn_kernel(
    const int* __restrict__ tokens, const float* __restrict__ hidden,
    const float* __restrict__ enc, const float* __restrict__ emb,
    const float* __restrict__ attn_W, const float* __restrict__ attn_b,
    float* __restrict__ cat_out, float* __restrict__ attn_w_out)
{
    const int b = blockIdx.x;
    const int tid = threadIdx.x;
    const int tok = tokens[b];
    const float* erow = emb + (size_t)tok * H_SZ;
    const float* hrow = hidden + (size_t)b * H_SZ;

    __shared__ float red[L_SZ][256];
    __shared__ float wts[L_SZ];

    float acc[L_SZ];
#pragma unroll
    for (int l = 0; l < L_SZ; ++l) acc[l] = 0.f;

    for (int i = tid; i < H_SZ; i += 256) {
        float e = erow[i];
        float hv = hrow[i];
        cat_out[(size_t)b * 2 * H_SZ + i] = e;
#pragma unroll
        for (int l = 0; l < L_SZ; ++l) {
            acc[l] += e * attn_W[l * 2 * H_SZ + i] + hv * attn_W[l * 2 * H_SZ + H_SZ + i];
        }
    }
#pragma unroll
    for (int l = 0; l < L_SZ; ++l) red[l][tid] = acc[l];
    __syncthreads();
    for (int s = 128; s > 0; s >>= 1) {
        if (tid < s) {
#pragma unroll
            for (int l = 0; l < L_SZ; ++l) red[l][tid] += red[l][tid + s];
        }
        __syncthreads();
    }
    if (tid == 0) {
        float m = -INFINITY;
        float lg[L_SZ];
#pragma unroll
        for (int l = 0; l < L_SZ; ++l) {
            lg[l] = red[l][0] + attn_b[l];
            m = fmaxf(m, lg[l]);
        }
        float s = 0.f;
#pragma unroll
        for (int l = 0; l < L_SZ; ++l) {
            float e = expf(lg[l] - m);
            wts[l] = e;
            s += e;
        }
        float inv = 1.f / s;
#pragma unroll
        for (int l = 0; l < L_SZ; ++l) {
            wts[l] *= inv;
            attn_w_out[(size_t)b * L_SZ + l] = wts[l];
        }
    }
    __syncthreads();

    for (int i = tid; i < H_SZ; i += 256) {
        float s = 0.f;
#pragma unroll
        for (int l = 0; l < L_SZ; ++l) s += wts[l] * enc[l * H_SZ + i];
        cat_out[(size_t)b * 2 * H_SZ + H_SZ + i] = s;
    }
}

// ---------------------------------------------------------------------------
// GRU pointwise combine
// ---------------------------------------------------------------------------
__global__ __launch_bounds__(256) void gru_combine(
    const float* __restrict__ gi, const float* __restrict__ gh,
    const float* __restrict__ hidden, float* __restrict__ h_new)
{
    int idx = blockIdx.x * blockDim.x + threadIdx.x;
    if (idx >= B_SZ * H_SZ) return;
    int b = idx >> 10;
    int j = idx & (H_SZ - 1);
    const float* gib = gi + (size_t)b * 3 * H_SZ;
    const float* ghb = gh + (size_t)b * 3 * H_SZ;
    float i_r = gib[j], i_z = gib[H_SZ + j], i_n = gib[2 * H_SZ + j];
    float h_r = ghb[j], h_z = ghb[H_SZ + j], h_n = ghb[2 * H_SZ + j];
    float r = 1.f / (1.f + expf(-(i_r + h_r)));
    float z = 1.f / (1.f + expf(-(i_z + h_z)));
    float n = tanhf(i_n + r * h_n);
    float h = hidden[idx];
    h_new[idx] = (1.f - z) * n + z * h;
}

// ---------------------------------------------------------------------------
// log-softmax, 2 passes, float4, online max+sum. One block (1024 thr) per row.
// Rows are only 4B-aligned (V odd) -> scalar head/tail around aligned body.
// ---------------------------------------------------------------------------
__global__ __launch_bounds__(1024) void logsoftmax_v2(float* __restrict__ out)
{
    const int b = blockIdx.x;
    float* row = out + (size_t)b * V_SZ;
    const int tid = threadIdx.x;
    const int wave = tid >> 6;
    const int lane = tid & 63;

    const int head = (int)(((16u - ((uintptr_t)row & 15u)) & 15u) >> 2);  // 0..3
    const int nv = (V_SZ - head) >> 2;
    const float4* r4 = (const float4*)(row + head);
    const int tail_start = head + (nv << 2);

    float m = -INFINITY, s = 0.f;
    if (tid < head) {
        float v = row[tid];
        m = v; s = 1.f;
    }
    for (int i = tid; i < nv; i += 1024) {
        float4 v = r4[i];
        float mv = fmaxf(fmaxf(v.x, v.y), fmaxf(v.z, v.w));
        if (mv > m) { s *= expf(m - mv); m = mv; }
        s += expf(v.x - m) + expf(v.y - m) + expf(v.z - m) + expf(v.w - m);
    }
    for (int i = tail_start + tid; i < V_SZ; i += 1024) {
        float v = row[i];
        if (v > m) { s *= expf(m - v); m = v; }
        s += expf(v - m);
    }

    // wave reduce (m,s)
    for (int off = 32; off > 0; off >>= 1) {
        float m2 = __shfl_down(m, off);
        float s2 = __shfl_down(s, off);
        float mn = fmaxf(m, m2);
        s = s * expf(m - mn) + s2 * expf(m2 - mn);
        m = mn;
    }
    __shared__ float smax[16], ssum[16], slse;
    if (lane == 0) { smax[wave] = m; ssum[wave] = s; }
    __syncthreads();
    if (tid == 0) {
        float M = smax[0], S = ssum[0];
        for (int w = 1; w < 16; ++w) {
            float mn = fmaxf(M, smax[w]);
            S = S * expf(M - mn) + ssum[w] * expf(smax[w] - mn);
            M = mn;
        }
        slse = M + logf(S);
    }
    __syncthreads();
    const float lse = slse;

    if (tid < head) row[tid] -= lse;
    float4* w4 = (float4*)(row + head);
    for (int i = tid; i < nv; i += 1024) {
        float4 v = r4[i];
        v.x -= lse; v.y -= lse; v.z -= lse; v.w -= lse;
        w4[i] = v;
    }
    for (int i = tail_start + tid; i < V_SZ; i += 1024) row[i] -= lse;
}

// ---------------------------------------------------------------------------
extern "C" void kernel_launch(void* const* d_in, const int* in_sizes, int n_in,
                              void* d_out, int out_size, void* d_ws, size_t ws_size,
                              hipStream_t stream)
{
    const int*   tokens = (const int*)d_in[0];
    const float* hidden = (const float*)d_in[1];
    const float* enc    = (const float*)d_in[2];
    const float* emb    = (const float*)d_in[3];
    const float* attn_W = (const float*)d_in[4];
    const float* attn_b = (const float*)d_in[5];
    const float* comb_W = (const float*)d_in[6];
    const float* comb_b = (const float*)d_in[7];
    const float* W_ih   = (const float*)d_in[8];
    const float* W_hh   = (const float*)d_in[9];
    const float* b_ih   = (const float*)d_in[10];
    const float* b_hh   = (const float*)d_in[11];
    const float* out_W  = (const float*)d_in[12];
    const float* out_b  = (const float*)d_in[13];

    float* out = (float*)d_out;
    float* logits     = out;                                   // [B,V]
    float* h_new      = out + (size_t)B_SZ * V_SZ;             // [B,H]
    float* attn_w_out = h_new + (size_t)B_SZ * H_SZ;           // [B,L]

    // Scratch in out-region-0 (dead before the big GEMM overwrites it)
    float* cat = logits;                          // [B, 2H]
    float* x   = cat + (size_t)B_SZ * 2 * H_SZ;   // [B, H]
    float* gi  = x   + (size_t)B_SZ * H_SZ;       // [B, 3H]
    float* gh  = gi  + (size_t)B_SZ * 3 * H_SZ;   // [B, 3H]

    attn_kernel<<<B_SZ, 256, 0, stream>>>(tokens, hidden, enc, emb, attn_W, attn_b,
                                          cat, attn_w_out);
    // x = relu(cat @ comb_W^T + comb_b)          [256 x 1024, K=2048]
    gemm_mfma<1, 1><<<dim3(H_SZ / 64, 4), 256, 0, stream>>>(
        cat, comb_W, comb_b, x, H_SZ, 2 * H_SZ);
    // gi = x @ W_ih^T + b_ih                     [256 x 3072, K=1024]
    gemm_mfma<1, 0><<<dim3(3 * H_SZ / 64, 4), 256, 0, stream>>>(
        x, W_ih, b_ih, gi, 3 * H_SZ, H_SZ);
    // gh = h @ W_hh^T + b_hh                     [256 x 3072, K=1024]
    gemm_mfma<1, 0><<<dim3(3 * H_SZ / 64, 4), 256, 0, stream>>>(
        hidden, W_hh, b_hh, gh, 3 * H_SZ, H_SZ);
    gru_combine<<<(B_SZ * H_SZ + 255) / 256, 256, 0, stream>>>(gi, gh, hidden, h_new);
    // logits = h_new @ out_W^T + out_b           [256 x 50257, K=1024]
    gemm_mfma<4, 0><<<dim3((V_SZ + 63) / 64, 1), 256, 0, stream>>>(
        h_new, out_W, out_b, logits, V_SZ, H_SZ);
    logsoftmax_v2<<<B_SZ, 1024, 0, stream>>>(logits);
}